// Round 14
// baseline (427.797 us; speedup 1.0000x reference)
//
#include <hip/hip_runtime.h>
#include <math.h>

// GCN 5-layer: per layer relu(A @ (h @ W) + b), A = sym-normalized adj w/ self-loops.
// CSR-by-dst radix build; aggregate on the narrow side of each GEMM; dinv folded
// into GEMM epilogues. All fp32.
// Agg: R5-R13 evidence -> gather rate pins at ~3.5TB/s (per-CU vmem/miss ceiling);
// best shape = R11 group-owns-row DEPTH 3/4 (67.5us, 43% occ). Locked.
// R14: GEMMs were LDS-read-bound (b32 xl reads: 35cy LDS vs 32cy FMA per k).
// New shape: 8 cols/thread x NR rows, k-block 4, xl read as float4 (stride IN+4)
// -> (8+NR) b128 per 4k = FMA-bound. Build: fixed-capacity bins (R13).

#define NBIN_MAX 256
#define BSHIFT 9
#define BINW 512
#define CHUNK 2048
#define BCAP 12288

// ---------------- graph build ----------------
__global__ __launch_bounds__(256) void k_init(int* __restrict__ binCur, int nbin) {
    int t = threadIdx.x;
    if (t < nbin) binCur[t] = t * BCAP;
}

__global__ __launch_bounds__(256) void k_binfill(const int* __restrict__ src,
                                                 const int* __restrict__ dst, int E,
                                                 int nbin, int* __restrict__ binCur,
                                                 unsigned* __restrict__ tmp) {
    __shared__ int h[NBIN_MAX];
    __shared__ int res[NBIN_MAX];
    int t = threadIdx.x;
    int e0 = blockIdx.x * CHUNK;
    int e1 = min(e0 + CHUNK, E);
    int vend = e0 + ((e1 - e0) & ~3);
    for (int i = t; i < nbin; i += 256) h[i] = 0;
    __syncthreads();
    for (int e = e0 + t * 4; e < vend; e += 1024) {
        int4 d = *(const int4*)&dst[e];
        atomicAdd(&h[d.x >> BSHIFT], 1);
        atomicAdd(&h[d.y >> BSHIFT], 1);
        atomicAdd(&h[d.z >> BSHIFT], 1);
        atomicAdd(&h[d.w >> BSHIFT], 1);
    }
    for (int e = vend + t; e < e1; e += 256)
        atomicAdd(&h[dst[e] >> BSHIFT], 1);
    __syncthreads();
    for (int i = t; i < nbin; i += 256)
        res[i] = h[i] ? atomicAdd(&binCur[i], h[i]) : 0;
    __syncthreads();
    for (int i = t; i < nbin; i += 256) h[i] = 0;
    __syncthreads();
    for (int e = e0 + t * 4; e < vend; e += 1024) {
        int4 d = *(const int4*)&dst[e];
        int4 s = *(const int4*)&src[e];
        int b0 = d.x >> BSHIFT;
        int p0 = res[b0] + atomicAdd(&h[b0], 1);
        tmp[p0] = ((unsigned)s.x << BSHIFT) | (unsigned)(d.x & (BINW - 1));
        int b1 = d.y >> BSHIFT;
        int p1 = res[b1] + atomicAdd(&h[b1], 1);
        tmp[p1] = ((unsigned)s.y << BSHIFT) | (unsigned)(d.y & (BINW - 1));
        int b2 = d.z >> BSHIFT;
        int p2 = res[b2] + atomicAdd(&h[b2], 1);
        tmp[p2] = ((unsigned)s.z << BSHIFT) | (unsigned)(d.z & (BINW - 1));
        int b3 = d.w >> BSHIFT;
        int p3 = res[b3] + atomicAdd(&h[b3], 1);
        tmp[p3] = ((unsigned)s.w << BSHIFT) | (unsigned)(d.w & (BINW - 1));
    }
    for (int e = vend + t; e < e1; e += 256) {
        int d = dst[e];
        int b = d >> BSHIFT;
        int p = res[b] + atomicAdd(&h[b], 1);
        tmp[p] = ((unsigned)src[e] << BSHIFT) | (unsigned)(d & (BINW - 1));
    }
}

__global__ __launch_bounds__(256) void k_base(const int* __restrict__ binCur,
                                              int nbin, int* __restrict__ binBase) {
    __shared__ int sh[256];
    int t = threadIdx.x;
    int c = (t < nbin) ? (binCur[t] - t * BCAP) : 0;
    sh[t] = c;
    __syncthreads();
    for (int d = 1; d < 256; d <<= 1) {
        int u = (t >= d) ? sh[t - d] : 0;
        __syncthreads();
        sh[t] += u;
        __syncthreads();
    }
    if (t < nbin) binBase[t] = sh[t] - c;
    if (t == nbin - 1) binBase[nbin] = sh[t];
}

__global__ __launch_bounds__(256) void k_csr(const unsigned* __restrict__ tmp,
                                             const int* __restrict__ binBase,
                                             int n, int nbin,
                                             float* __restrict__ dinv,
                                             int* __restrict__ offs,
                                             int* __restrict__ csr) {
    __shared__ int ldeg[BINW];
    __shared__ int loff[BINW];
    __shared__ int pair[256];
    int b = blockIdx.x;
    int t = threadIdx.x;
    ldeg[t] = 0; ldeg[t + 256] = 0;
    __syncthreads();
    int lo = binBase[b];
    int cnt = binBase[b + 1] - lo;
    const unsigned* tb = tmp + (size_t)b * BCAP;
    for (int p = t; p < cnt; p += 256)
        atomicAdd(&ldeg[tb[p] & (BINW - 1u)], 1);
    __syncthreads();
    int a0 = ldeg[2 * t], a1 = ldeg[2 * t + 1];
    pair[t] = a0 + a1;
    __syncthreads();
    int v = pair[t];
    for (int d = 1; d < 256; d <<= 1) {
        int u = (t >= d) ? pair[t - d] : 0;
        __syncthreads();
        pair[t] += u;
        __syncthreads();
    }
    int ex = pair[t] - v;
    loff[2 * t] = ex;
    loff[2 * t + 1] = ex + a0;
    __syncthreads();
    int v0 = b << BSHIFT;
    for (int i = t; i < BINW; i += 256) {
        int vv = v0 + i;
        if (vv < n) {
            offs[vv] = lo + loff[i];
            dinv[vv] = 1.0f / sqrtf((float)(ldeg[i] + 1));
        }
    }
    if (t == 0 && b == nbin - 1) offs[n] = binBase[nbin];
    __syncthreads();
    ldeg[t] = 0; ldeg[t + 256] = 0;
    __syncthreads();
    for (int p = t; p < cnt; p += 256) {
        unsigned u = tb[p];
        int d0 = (int)(u & (BINW - 1u));
        int pos = loff[d0] + atomicAdd(&ldeg[d0], 1);
        csr[lo + pos] = (int)(u >> BSHIFT);
    }
}

// ---------------- aggregation: group-owns-row, depth-pipelined (R11 exact) ----------------
template <int W, int DEPTH, bool RELU, bool BIAS, bool L1S>
__global__ __launch_bounds__(256) void k_aggp(const float* __restrict__ S,
                                              const float* __restrict__ dinv,
                                              const int* __restrict__ offs,
                                              const int* __restrict__ csr,
                                              const float* __restrict__ bg,
                                              float* __restrict__ Y, int n) {
    constexpr int LPR = W / 4;
    constexpr int GPW = 64 / LPR;
    int lane = threadIdx.x & 63;
    int wave = threadIdx.x >> 6;
    int grp = lane / LPR;
    int j = lane % LPR;
    int v = blockIdx.x * (4 * GPW) + wave * GPW + grp;
    if (v >= n) return;
    float dv = dinv[v];
    float4 acc0, acc1 = make_float4(0.f, 0.f, 0.f, 0.f);
    {
        float4 sv = *(const float4*)&S[(size_t)v * W + j * 4];
        float sc = L1S ? dv : 1.0f;
        acc0 = make_float4(sv.x * sc, sv.y * sc, sv.z * sc, sv.w * sc);
    }
    int e0 = offs[v], re = offs[v + 1];
    int nb = (re - e0) / DEPTH;
    float4 bA[DEPTH], bB[DEPTH];
    float dA[DEPTH], dB[DEPTH];
    int iA[DEPTH], iB[DEPTH];
    auto loadIdx = [&](int* ix, int base) {
#pragma unroll
        for (int d = 0; d < DEPTH; ++d)
            ix[d] = __builtin_nontemporal_load(&csr[base + d]);
    };
    auto gather = [&](float4* bf, float* ds, const int* ix) {
#pragma unroll
        for (int d = 0; d < DEPTH; ++d) {
            bf[d] = *(const float4*)&S[(size_t)ix[d] * W + j * 4];
            if (L1S) ds[d] = dinv[ix[d]];
        }
    };
    auto consume = [&](const float4* bf, const float* ds) {
#pragma unroll
        for (int d = 0; d < DEPTH; ++d) {
            float sc = L1S ? ds[d] : 1.0f;
            if (d & 1) { acc1.x += bf[d].x * sc; acc1.y += bf[d].y * sc;
                         acc1.z += bf[d].z * sc; acc1.w += bf[d].w * sc; }
            else       { acc0.x += bf[d].x * sc; acc0.y += bf[d].y * sc;
                         acc0.z += bf[d].z * sc; acc0.w += bf[d].w * sc; }
        }
    };
    if (nb >= 1) {
        loadIdx(iA, e0);
        gather(bA, dA, iA);
        if (nb >= 2) loadIdx(iB, e0 + DEPTH);
        int b = 0;
        while (b + 2 <= nb) {
            gather(bB, dB, iB);
            if (b + 2 < nb) loadIdx(iA, e0 + (b + 2) * DEPTH);
            consume(bA, dA);
            if (b + 2 < nb) {
                gather(bA, dA, iA);
                if (b + 3 < nb) loadIdx(iB, e0 + (b + 3) * DEPTH);
            }
            consume(bB, dB);
            b += 2;
        }
        if (b < nb) consume(bA, dA);
    }
    for (int k = e0 + nb * DEPTH; k < re; ++k) {
        int u = __builtin_nontemporal_load(&csr[k]);
        float4 a = *(const float4*)&S[(size_t)u * W + j * 4];
        float sc = L1S ? dinv[u] : 1.0f;
        acc0.x += a.x * sc; acc0.y += a.y * sc; acc0.z += a.z * sc; acc0.w += a.w * sc;
    }
    acc0.x += acc1.x; acc0.y += acc1.y; acc0.z += acc1.z; acc0.w += acc1.w;
    float4 r;
    r.x = dv * acc0.x; r.y = dv * acc0.y; r.z = dv * acc0.z; r.w = dv * acc0.w;
    if (BIAS) {
        float4 bv = *(const float4*)&bg[j * 4];
        r.x += bv.x; r.y += bv.y; r.z += bv.z; r.w += bv.w;
    }
    if (RELU) {
        r.x = fmaxf(r.x, 0.f); r.y = fmaxf(r.y, 0.f);
        r.z = fmaxf(r.z, 0.f); r.w = fmaxf(r.w, 0.f);
    }
    *(float4*)&Y[(size_t)v * W + j * 4] = r;
}

// W=16 agg + gemm5 fused, group-owns-row (4-lane groups)
template <int DEPTH>
__global__ __launch_bounds__(256) void k_agg16g5(const float* __restrict__ S,
                                                 const float* __restrict__ dinv,
                                                 const int* __restrict__ offs,
                                                 const int* __restrict__ csr,
                                                 const float* __restrict__ b4,
                                                 const float* __restrict__ W5,
                                                 float* __restrict__ Y, int n) {
    constexpr int W = 16, LPR = 4, GPW = 16;
    int lane = threadIdx.x & 63;
    int wave = threadIdx.x >> 6;
    int grp = lane / LPR;
    int j = lane % LPR;
    int v = blockIdx.x * (4 * GPW) + wave * GPW + grp;
    if (v >= n) return;
    float dv = dinv[v];
    float4 acc0 = *(const float4*)&S[(size_t)v * W + j * 4];
    float4 acc1 = make_float4(0.f, 0.f, 0.f, 0.f);
    int e0 = offs[v], re = offs[v + 1];
    int nb = (re - e0) / DEPTH;
    float4 bA[DEPTH], bB[DEPTH];
    int iA[DEPTH], iB[DEPTH];
    auto loadIdx = [&](int* ix, int base) {
#pragma unroll
        for (int d = 0; d < DEPTH; ++d)
            ix[d] = __builtin_nontemporal_load(&csr[base + d]);
    };
    auto gather = [&](float4* bf, const int* ix) {
#pragma unroll
        for (int d = 0; d < DEPTH; ++d)
            bf[d] = *(const float4*)&S[(size_t)ix[d] * W + j * 4];
    };
    auto consume = [&](const float4* bf) {
#pragma unroll
        for (int d = 0; d < DEPTH; ++d) {
            if (d & 1) { acc1.x += bf[d].x; acc1.y += bf[d].y;
                         acc1.z += bf[d].z; acc1.w += bf[d].w; }
            else       { acc0.x += bf[d].x; acc0.y += bf[d].y;
                         acc0.z += bf[d].z; acc0.w += bf[d].w; }
        }
    };
    if (nb >= 1) {
        loadIdx(iA, e0);
        gather(bA, iA);
        if (nb >= 2) loadIdx(iB, e0 + DEPTH);
        int b = 0;
        while (b + 2 <= nb) {
            gather(bB, iB);
            if (b + 2 < nb) loadIdx(iA, e0 + (b + 2) * DEPTH);
            consume(bA);
            if (b + 2 < nb) {
                gather(bA, iA);
                if (b + 3 < nb) loadIdx(iB, e0 + (b + 3) * DEPTH);
            }
            consume(bB);
            b += 2;
        }
        if (b < nb) consume(bA);
    }
    for (int k = e0 + nb * DEPTH; k < re; ++k) {
        int u = __builtin_nontemporal_load(&csr[k]);
        float4 a = *(const float4*)&S[(size_t)u * W + j * 4];
        acc0.x += a.x; acc0.y += a.y; acc0.z += a.z; acc0.w += a.w;
    }
    acc0.x += acc1.x; acc0.y += acc1.y; acc0.z += acc1.z; acc0.w += acc1.w;
    float4 bv = *(const float4*)&b4[j * 4];
    float4 w5 = *(const float4*)&W5[j * 4];
    float hx = fmaxf(dv * acc0.x + bv.x, 0.f);
    float hy = fmaxf(dv * acc0.y + bv.y, 0.f);
    float hz = fmaxf(dv * acc0.z + bv.z, 0.f);
    float hw = fmaxf(dv * acc0.w + bv.w, 0.f);
    float p = hx * w5.x + hy * w5.y + hz * w5.z + hw * w5.w;
    p += __shfl_xor(p, 1);
    p += __shfl_xor(p, 2);
    if (j == 0) Y[v] = p * dv;
}

__global__ __launch_bounds__(256) void k_agg1(const float* __restrict__ S,
                                              const float* __restrict__ dinv,
                                              const int* __restrict__ offs,
                                              const int* __restrict__ csr,
                                              const float* __restrict__ bg,
                                              float* __restrict__ Y, int n) {
    int v = blockIdx.x * 256 + threadIdx.x;
    if (v >= n) return;
    float s0 = S[v], s1 = 0.f, s2 = 0.f, s3 = 0.f;
    int e = offs[v], re = offs[v + 1];
    for (; e + 4 <= re; e += 4) {
        int i0 = csr[e], i1 = csr[e + 1], i2 = csr[e + 2], i3 = csr[e + 3];
        s0 += S[i0]; s1 += S[i1]; s2 += S[i2]; s3 += S[i3];
    }
    for (; e < re; ++e) s0 += S[csr[e]];
    Y[v] = dinv[v] * ((s0 + s1) + (s2 + s3)) + bg[0];
}

// ---------------- tall-skinny GEMMs: 8 cols/thread, k-block 4, all-float4 LDS ----------------
// EPI==0: += bias, relu.  EPI==1: *= dinv[row].
template <int IN, int OUT, int EPI, int NR>
__global__ __launch_bounds__(256) void k_gemm(const float* __restrict__ X,
                                              const float* __restrict__ Wg,
                                              const float* __restrict__ bg,
                                              const float* __restrict__ dinv,
                                              float* __restrict__ Y, int nrows) {
    constexpr int TPR = OUT / 8;          // threads per row (8 cols each)
    constexpr int GROUPS = 256 / TPR;
    constexpr int ROWS = GROUPS * NR;
    constexpr int XS = IN + 4;            // padded, float4-aligned
    __shared__ __align__(16) float Wl[IN * OUT];
    __shared__ __align__(16) float xl[ROWS * XS];
    __shared__ float bl[OUT];
    int tid = threadIdx.x;
    for (int i = tid; i < IN * OUT / 4; i += 256)
        ((float4*)Wl)[i] = ((const float4*)Wg)[i];
    if (EPI == 0)
        for (int i = tid; i < OUT; i += 256) bl[i] = bg[i];
    int base = blockIdx.x * ROWS;
    for (int i = tid; i < ROWS * (IN / 4); i += 256) {
        int r = i / (IN / 4), c4 = i % (IN / 4);
        int row = base + r;
        float4 vv = (row < nrows) ? ((const float4*)X)[(size_t)base * (IN / 4) + i]
                                  : make_float4(0.f, 0.f, 0.f, 0.f);
        *(float4*)&xl[r * XS + c4 * 4] = vv;
    }
    __syncthreads();
    int g = tid / TPR;
    int c0 = (tid % TPR) * 8;
    float4 acc[NR][2];
#pragma unroll
    for (int r = 0; r < NR; ++r) {
        acc[r][0] = make_float4(0.f, 0.f, 0.f, 0.f);
        acc[r][1] = make_float4(0.f, 0.f, 0.f, 0.f);
    }
    for (int k4 = 0; k4 < IN; k4 += 4) {
        float4 a[NR];
#pragma unroll
        for (int r = 0; r < NR; ++r)
            a[r] = *(const float4*)&xl[(g * NR + r) * XS + k4];
#pragma unroll
        for (int kk = 0; kk < 4; ++kk) {
            float4 w0 = *(const float4*)&Wl[(k4 + kk) * OUT + c0];
            float4 w1 = *(const float4*)&Wl[(k4 + kk) * OUT + c0 + 4];
#pragma unroll
            for (int r = 0; r < NR; ++r) {
                float av = (kk == 0) ? a[r].x : (kk == 1) ? a[r].y
                         : (kk == 2) ? a[r].z : a[r].w;
                acc[r][0].x += av * w0.x; acc[r][0].y += av * w0.y;
                acc[r][0].z += av * w0.z; acc[r][0].w += av * w0.w;
                acc[r][1].x += av * w1.x; acc[r][1].y += av * w1.y;
                acc[r][1].z += av * w1.z; acc[r][1].w += av * w1.w;
            }
        }
    }
#pragma unroll
    for (int r = 0; r < NR; ++r) {
        int row = base + g * NR + r;
        if (row >= nrows) continue;
        float4 o0 = acc[r][0], o1 = acc[r][1];
        if (EPI == 0) {
            o0.x = fmaxf(o0.x + bl[c0 + 0], 0.f);
            o0.y = fmaxf(o0.y + bl[c0 + 1], 0.f);
            o0.z = fmaxf(o0.z + bl[c0 + 2], 0.f);
            o0.w = fmaxf(o0.w + bl[c0 + 3], 0.f);
            o1.x = fmaxf(o1.x + bl[c0 + 4], 0.f);
            o1.y = fmaxf(o1.y + bl[c0 + 5], 0.f);
            o1.z = fmaxf(o1.z + bl[c0 + 6], 0.f);
            o1.w = fmaxf(o1.w + bl[c0 + 7], 0.f);
        } else {
            float d0 = dinv[row];
            o0.x *= d0; o0.y *= d0; o0.z *= d0; o0.w *= d0;
            o1.x *= d0; o1.y *= d0; o1.z *= d0; o1.w *= d0;
        }
        *(float4*)&Y[(size_t)row * OUT + c0] = o0;
        *(float4*)&Y[(size_t)row * OUT + c0 + 4] = o1;
    }
}

extern "C" void kernel_launch(void* const* d_in, const int* in_sizes, int n_in,
                              void* d_out, int out_size, void* d_ws, size_t ws_size,
                              hipStream_t stream) {
    const float* x  = (const float*)d_in[0];
    const int*   ei = (const int*)d_in[1];
    const float* W1 = (const float*)d_in[2];  const float* b1 = (const float*)d_in[3];
    const float* W2 = (const float*)d_in[4];  const float* b2 = (const float*)d_in[5];
    const float* W3 = (const float*)d_in[6];  const float* b3 = (const float*)d_in[7];
    const float* W4 = (const float*)d_in[8];  const float* b4 = (const float*)d_in[9];
    const float* W5 = (const float*)d_in[10]; const float* b5 = (const float*)d_in[11];

    const int N = in_sizes[0] / 64;   // 100000
    const int E = in_sizes[1] / 2;    // 1600000
    const int* src = ei;
    const int* dst = ei + E;
    const int nbin = (N + BINW - 1) / BINW;   // 196

    char* ws = (char*)d_ws;
    size_t off = 0;
    auto alloc = [&](size_t bytes) -> void* {
        void* p = ws + off;
        off = (off + bytes + 255) & ~(size_t)255;
        return p;
    };
    float* dinv    = (float*)alloc((size_t)N * 4);
    int*   offs    = (int*)alloc((size_t)(N + 1) * 4);
    int*   binBase = (int*)alloc((size_t)(NBIN_MAX + 1) * 4);
    int*   binCur  = (int*)alloc((size_t)NBIN_MAX * 4);
    int*   csr     = (int*)alloc((size_t)E * 4);
    float* s5      = (float*)alloc((size_t)N * 4);
    float* A       = (float*)alloc((size_t)N * 128 * 4);  // h1 -> h3
    float* B       = (float*)alloc((size_t)N * 64 * 4);   // agg1/s2/s3/s4
    float* C       = (float*)alloc((size_t)N * 64 * 4);   // tmp -> h2
    unsigned* tmp  = (unsigned*)C;

    k_init<<<1, 256, 0, stream>>>(binCur, nbin);
    k_binfill<<<(E + CHUNK - 1) / CHUNK, 256, 0, stream>>>(src, dst, E, nbin, binCur, tmp);
    k_base<<<1, 256, 0, stream>>>(binCur, nbin, binBase);
    k_csr<<<nbin, 256, 0, stream>>>(tmp, binBase, N, nbin, dinv, offs, csr);

    // Layer 1 (agg DEPTH=3, R11 exact)
    k_aggp<64, 3, false, false, true><<<(N + 15) / 16, 256, 0, stream>>>(x, dinv, offs, csr, nullptr, B, N);
    k_gemm<64, 128, 0, 4><<<(N + 63) / 64, 256, 0, stream>>>(B, W1, b1, nullptr, A, N);
    // Layer 2 (agg DEPTH=4)
    k_gemm<128, 64, 1, 2><<<(N + 63) / 64, 256, 0, stream>>>(A, W2, nullptr, dinv, B, N);
    k_aggp<64, 4, true, true, false><<<(N + 15) / 16, 256, 0, stream>>>(B, dinv, offs, csr, b2, C, N);
    // Layer 3
    k_gemm<64, 32, 1, 2><<<(N + 127) / 128, 256, 0, stream>>>(C, W3, nullptr, dinv, B, N);
    k_aggp<32, 4, true, true, false><<<(N + 31) / 32, 256, 0, stream>>>(B, dinv, offs, csr, b3, A, N);
    // Layer 4
    k_gemm<32, 16, 1, 2><<<(N + 255) / 256, 256, 0, stream>>>(A, W4, nullptr, dinv, B, N);
    k_agg16g5<4><<<(N + 63) / 64, 256, 0, stream>>>(B, dinv, offs, csr, b4, W5, s5, N);
    // Layer 5
    k_agg1<<<(N + 255) / 256, 256, 0, stream>>>(s5, dinv, offs, csr, b5, (float*)d_out, N);
}

// Round 15
// 382.284 us; speedup vs baseline: 1.1191x; 1.1191x over previous
//
#include <hip/hip_runtime.h>
#include <math.h>

// GCN 5-layer: per layer relu(A @ (h @ W) + b), A = sym-normalized adj w/ self-loops.
// CSR-by-dst radix build; aggregate on the narrow side of each GEMM; dinv folded
// into GEMM epilogues. All fp32.
// CONVERGED CONFIG (R15): best-known per component.
// - Build: fixed-capacity bins (R13), ~45us.
// - Aggs: R11-exact group-owns-row DEPTH 3/4 (67.5us @43% occ, 3.55TB/s).
//   Evidence R5-R13: six structures pin at 2.9-3.55TB/s -> random-gather ceiling;
//   DEPTH/LDS/edge-parallel variants all traded occupancy for MLP at a net loss.
// - GEMMs: R13 shape (4 cols/thread, xl stride IN+1, NR=4/2/2/2). R14's 8-col
//   k-blocked variant hit VGPR=256 / 9% occupancy -> 2.5x regression, reverted.

#define NBIN_MAX 256
#define BSHIFT 9
#define BINW 512
#define CHUNK 2048
#define BCAP 12288

// ---------------- graph build ----------------
__global__ __launch_bounds__(256) void k_init(int* __restrict__ binCur, int nbin) {
    int t = threadIdx.x;
    if (t < nbin) binCur[t] = t * BCAP;
}

__global__ __launch_bounds__(256) void k_binfill(const int* __restrict__ src,
                                                 const int* __restrict__ dst, int E,
                                                 int nbin, int* __restrict__ binCur,
                                                 unsigned* __restrict__ tmp) {
    __shared__ int h[NBIN_MAX];
    __shared__ int res[NBIN_MAX];
    int t = threadIdx.x;
    int e0 = blockIdx.x * CHUNK;
    int e1 = min(e0 + CHUNK, E);
    int vend = e0 + ((e1 - e0) & ~3);
    for (int i = t; i < nbin; i += 256) h[i] = 0;
    __syncthreads();
    for (int e = e0 + t * 4; e < vend; e += 1024) {
        int4 d = *(const int4*)&dst[e];
        atomicAdd(&h[d.x >> BSHIFT], 1);
        atomicAdd(&h[d.y >> BSHIFT], 1);
        atomicAdd(&h[d.z >> BSHIFT], 1);
        atomicAdd(&h[d.w >> BSHIFT], 1);
    }
    for (int e = vend + t; e < e1; e += 256)
        atomicAdd(&h[dst[e] >> BSHIFT], 1);
    __syncthreads();
    for (int i = t; i < nbin; i += 256)
        res[i] = h[i] ? atomicAdd(&binCur[i], h[i]) : 0;
    __syncthreads();
    for (int i = t; i < nbin; i += 256) h[i] = 0;
    __syncthreads();
    for (int e = e0 + t * 4; e < vend; e += 1024) {
        int4 d = *(const int4*)&dst[e];
        int4 s = *(const int4*)&src[e];
        int b0 = d.x >> BSHIFT;
        int p0 = res[b0] + atomicAdd(&h[b0], 1);
        tmp[p0] = ((unsigned)s.x << BSHIFT) | (unsigned)(d.x & (BINW - 1));
        int b1 = d.y >> BSHIFT;
        int p1 = res[b1] + atomicAdd(&h[b1], 1);
        tmp[p1] = ((unsigned)s.y << BSHIFT) | (unsigned)(d.y & (BINW - 1));
        int b2 = d.z >> BSHIFT;
        int p2 = res[b2] + atomicAdd(&h[b2], 1);
        tmp[p2] = ((unsigned)s.z << BSHIFT) | (unsigned)(d.z & (BINW - 1));
        int b3 = d.w >> BSHIFT;
        int p3 = res[b3] + atomicAdd(&h[b3], 1);
        tmp[p3] = ((unsigned)s.w << BSHIFT) | (unsigned)(d.w & (BINW - 1));
    }
    for (int e = vend + t; e < e1; e += 256) {
        int d = dst[e];
        int b = d >> BSHIFT;
        int p = res[b] + atomicAdd(&h[b], 1);
        tmp[p] = ((unsigned)src[e] << BSHIFT) | (unsigned)(d & (BINW - 1));
    }
}

__global__ __launch_bounds__(256) void k_base(const int* __restrict__ binCur,
                                              int nbin, int* __restrict__ binBase) {
    __shared__ int sh[256];
    int t = threadIdx.x;
    int c = (t < nbin) ? (binCur[t] - t * BCAP) : 0;
    sh[t] = c;
    __syncthreads();
    for (int d = 1; d < 256; d <<= 1) {
        int u = (t >= d) ? sh[t - d] : 0;
        __syncthreads();
        sh[t] += u;
        __syncthreads();
    }
    if (t < nbin) binBase[t] = sh[t] - c;
    if (t == nbin - 1) binBase[nbin] = sh[t];
}

__global__ __launch_bounds__(256) void k_csr(const unsigned* __restrict__ tmp,
                                             const int* __restrict__ binBase,
                                             int n, int nbin,
                                             float* __restrict__ dinv,
                                             int* __restrict__ offs,
                                             int* __restrict__ csr) {
    __shared__ int ldeg[BINW];
    __shared__ int loff[BINW];
    __shared__ int pair[256];
    int b = blockIdx.x;
    int t = threadIdx.x;
    ldeg[t] = 0; ldeg[t + 256] = 0;
    __syncthreads();
    int lo = binBase[b];
    int cnt = binBase[b + 1] - lo;
    const unsigned* tb = tmp + (size_t)b * BCAP;
    for (int p = t; p < cnt; p += 256)
        atomicAdd(&ldeg[tb[p] & (BINW - 1u)], 1);
    __syncthreads();
    int a0 = ldeg[2 * t], a1 = ldeg[2 * t + 1];
    pair[t] = a0 + a1;
    __syncthreads();
    int v = pair[t];
    for (int d = 1; d < 256; d <<= 1) {
        int u = (t >= d) ? pair[t - d] : 0;
        __syncthreads();
        pair[t] += u;
        __syncthreads();
    }
    int ex = pair[t] - v;
    loff[2 * t] = ex;
    loff[2 * t + 1] = ex + a0;
    __syncthreads();
    int v0 = b << BSHIFT;
    for (int i = t; i < BINW; i += 256) {
        int vv = v0 + i;
        if (vv < n) {
            offs[vv] = lo + loff[i];
            dinv[vv] = 1.0f / sqrtf((float)(ldeg[i] + 1));
        }
    }
    if (t == 0 && b == nbin - 1) offs[n] = binBase[nbin];
    __syncthreads();
    ldeg[t] = 0; ldeg[t + 256] = 0;
    __syncthreads();
    for (int p = t; p < cnt; p += 256) {
        unsigned u = tb[p];
        int d0 = (int)(u & (BINW - 1u));
        int pos = loff[d0] + atomicAdd(&ldeg[d0], 1);
        csr[lo + pos] = (int)(u >> BSHIFT);
    }
}

// ---------------- aggregation: group-owns-row, depth-pipelined (R11 exact) ----------------
template <int W, int DEPTH, bool RELU, bool BIAS, bool L1S>
__global__ __launch_bounds__(256) void k_aggp(const float* __restrict__ S,
                                              const float* __restrict__ dinv,
                                              const int* __restrict__ offs,
                                              const int* __restrict__ csr,
                                              const float* __restrict__ bg,
                                              float* __restrict__ Y, int n) {
    constexpr int LPR = W / 4;
    constexpr int GPW = 64 / LPR;
    int lane = threadIdx.x & 63;
    int wave = threadIdx.x >> 6;
    int grp = lane / LPR;
    int j = lane % LPR;
    int v = blockIdx.x * (4 * GPW) + wave * GPW + grp;
    if (v >= n) return;
    float dv = dinv[v];
    float4 acc0, acc1 = make_float4(0.f, 0.f, 0.f, 0.f);
    {
        float4 sv = *(const float4*)&S[(size_t)v * W + j * 4];
        float sc = L1S ? dv : 1.0f;
        acc0 = make_float4(sv.x * sc, sv.y * sc, sv.z * sc, sv.w * sc);
    }
    int e0 = offs[v], re = offs[v + 1];
    int nb = (re - e0) / DEPTH;
    float4 bA[DEPTH], bB[DEPTH];
    float dA[DEPTH], dB[DEPTH];
    int iA[DEPTH], iB[DEPTH];
    auto loadIdx = [&](int* ix, int base) {
#pragma unroll
        for (int d = 0; d < DEPTH; ++d)
            ix[d] = __builtin_nontemporal_load(&csr[base + d]);
    };
    auto gather = [&](float4* bf, float* ds, const int* ix) {
#pragma unroll
        for (int d = 0; d < DEPTH; ++d) {
            bf[d] = *(const float4*)&S[(size_t)ix[d] * W + j * 4];
            if (L1S) ds[d] = dinv[ix[d]];
        }
    };
    auto consume = [&](const float4* bf, const float* ds) {
#pragma unroll
        for (int d = 0; d < DEPTH; ++d) {
            float sc = L1S ? ds[d] : 1.0f;
            if (d & 1) { acc1.x += bf[d].x * sc; acc1.y += bf[d].y * sc;
                         acc1.z += bf[d].z * sc; acc1.w += bf[d].w * sc; }
            else       { acc0.x += bf[d].x * sc; acc0.y += bf[d].y * sc;
                         acc0.z += bf[d].z * sc; acc0.w += bf[d].w * sc; }
        }
    };
    if (nb >= 1) {
        loadIdx(iA, e0);
        gather(bA, dA, iA);
        if (nb >= 2) loadIdx(iB, e0 + DEPTH);
        int b = 0;
        while (b + 2 <= nb) {
            gather(bB, dB, iB);
            if (b + 2 < nb) loadIdx(iA, e0 + (b + 2) * DEPTH);
            consume(bA, dA);
            if (b + 2 < nb) {
                gather(bA, dA, iA);
                if (b + 3 < nb) loadIdx(iB, e0 + (b + 3) * DEPTH);
            }
            consume(bB, dB);
            b += 2;
        }
        if (b < nb) consume(bA, dA);
    }
    for (int k = e0 + nb * DEPTH; k < re; ++k) {
        int u = __builtin_nontemporal_load(&csr[k]);
        float4 a = *(const float4*)&S[(size_t)u * W + j * 4];
        float sc = L1S ? dinv[u] : 1.0f;
        acc0.x += a.x * sc; acc0.y += a.y * sc; acc0.z += a.z * sc; acc0.w += a.w * sc;
    }
    acc0.x += acc1.x; acc0.y += acc1.y; acc0.z += acc1.z; acc0.w += acc1.w;
    float4 r;
    r.x = dv * acc0.x; r.y = dv * acc0.y; r.z = dv * acc0.z; r.w = dv * acc0.w;
    if (BIAS) {
        float4 bv = *(const float4*)&bg[j * 4];
        r.x += bv.x; r.y += bv.y; r.z += bv.z; r.w += bv.w;
    }
    if (RELU) {
        r.x = fmaxf(r.x, 0.f); r.y = fmaxf(r.y, 0.f);
        r.z = fmaxf(r.z, 0.f); r.w = fmaxf(r.w, 0.f);
    }
    *(float4*)&Y[(size_t)v * W + j * 4] = r;
}

// W=16 agg + gemm5 fused, group-owns-row (4-lane groups)
template <int DEPTH>
__global__ __launch_bounds__(256) void k_agg16g5(const float* __restrict__ S,
                                                 const float* __restrict__ dinv,
                                                 const int* __restrict__ offs,
                                                 const int* __restrict__ csr,
                                                 const float* __restrict__ b4,
                                                 const float* __restrict__ W5,
                                                 float* __restrict__ Y, int n) {
    constexpr int W = 16, LPR = 4, GPW = 16;
    int lane = threadIdx.x & 63;
    int wave = threadIdx.x >> 6;
    int grp = lane / LPR;
    int j = lane % LPR;
    int v = blockIdx.x * (4 * GPW) + wave * GPW + grp;
    if (v >= n) return;
    float dv = dinv[v];
    float4 acc0 = *(const float4*)&S[(size_t)v * W + j * 4];
    float4 acc1 = make_float4(0.f, 0.f, 0.f, 0.f);
    int e0 = offs[v], re = offs[v + 1];
    int nb = (re - e0) / DEPTH;
    float4 bA[DEPTH], bB[DEPTH];
    int iA[DEPTH], iB[DEPTH];
    auto loadIdx = [&](int* ix, int base) {
#pragma unroll
        for (int d = 0; d < DEPTH; ++d)
            ix[d] = __builtin_nontemporal_load(&csr[base + d]);
    };
    auto gather = [&](float4* bf, const int* ix) {
#pragma unroll
        for (int d = 0; d < DEPTH; ++d)
            bf[d] = *(const float4*)&S[(size_t)ix[d] * W + j * 4];
    };
    auto consume = [&](const float4* bf) {
#pragma unroll
        for (int d = 0; d < DEPTH; ++d) {
            if (d & 1) { acc1.x += bf[d].x; acc1.y += bf[d].y;
                         acc1.z += bf[d].z; acc1.w += bf[d].w; }
            else       { acc0.x += bf[d].x; acc0.y += bf[d].y;
                         acc0.z += bf[d].z; acc0.w += bf[d].w; }
        }
    };
    if (nb >= 1) {
        loadIdx(iA, e0);
        gather(bA, iA);
        if (nb >= 2) loadIdx(iB, e0 + DEPTH);
        int b = 0;
        while (b + 2 <= nb) {
            gather(bB, iB);
            if (b + 2 < nb) loadIdx(iA, e0 + (b + 2) * DEPTH);
            consume(bA);
            if (b + 2 < nb) {
                gather(bA, iA);
                if (b + 3 < nb) loadIdx(iB, e0 + (b + 3) * DEPTH);
            }
            consume(bB);
            b += 2;
        }
        if (b < nb) consume(bA);
    }
    for (int k = e0 + nb * DEPTH; k < re; ++k) {
        int u = __builtin_nontemporal_load(&csr[k]);
        float4 a = *(const float4*)&S[(size_t)u * W + j * 4];
        acc0.x += a.x; acc0.y += a.y; acc0.z += a.z; acc0.w += a.w;
    }
    acc0.x += acc1.x; acc0.y += acc1.y; acc0.z += acc1.z; acc0.w += acc1.w;
    float4 bv = *(const float4*)&b4[j * 4];
    float4 w5 = *(const float4*)&W5[j * 4];
    float hx = fmaxf(dv * acc0.x + bv.x, 0.f);
    float hy = fmaxf(dv * acc0.y + bv.y, 0.f);
    float hz = fmaxf(dv * acc0.z + bv.z, 0.f);
    float hw = fmaxf(dv * acc0.w + bv.w, 0.f);
    float p = hx * w5.x + hy * w5.y + hz * w5.z + hw * w5.w;
    p += __shfl_xor(p, 1);
    p += __shfl_xor(p, 2);
    if (j == 0) Y[v] = p * dv;
}

__global__ __launch_bounds__(256) void k_agg1(const float* __restrict__ S,
                                              const float* __restrict__ dinv,
                                              const int* __restrict__ offs,
                                              const int* __restrict__ csr,
                                              const float* __restrict__ bg,
                                              float* __restrict__ Y, int n) {
    int v = blockIdx.x * 256 + threadIdx.x;
    if (v >= n) return;
    float s0 = S[v], s1 = 0.f, s2 = 0.f, s3 = 0.f;
    int e = offs[v], re = offs[v + 1];
    for (; e + 4 <= re; e += 4) {
        int i0 = csr[e], i1 = csr[e + 1], i2 = csr[e + 2], i3 = csr[e + 3];
        s0 += S[i0]; s1 += S[i1]; s2 += S[i2]; s3 += S[i3];
    }
    for (; e < re; ++e) s0 += S[csr[e]];
    Y[v] = dinv[v] * ((s0 + s1) + (s2 + s3)) + bg[0];
}

// ---------------- tall-skinny GEMMs (R13 shape: 4 cols/thread, padded xl) ----------------
template <int IN, int OUT, int EPI, int NR>
__global__ __launch_bounds__(256) void k_gemm(const float* __restrict__ X,
                                              const float* __restrict__ Wg,
                                              const float* __restrict__ bg,
                                              const float* __restrict__ dinv,
                                              float* __restrict__ Y, int nrows) {
    constexpr int TPR = OUT / 4;
    constexpr int GROUPS = 256 / TPR;
    constexpr int ROWS = GROUPS * NR;
    constexpr int XS = IN + 1;
    __shared__ __align__(16) float Wl[IN * OUT];
    __shared__ float xl[ROWS * XS];
    __shared__ float bl[OUT];
    int tid = threadIdx.x;
    for (int i = tid; i < IN * OUT; i += 256) Wl[i] = Wg[i];
    if (EPI == 0)
        for (int i = tid; i < OUT; i += 256) bl[i] = bg[i];
    int base = blockIdx.x * ROWS;
    for (int i = tid; i < ROWS * IN; i += 256) {
        int r = i / IN, c = i % IN;
        int row = base + r;
        xl[r * XS + c] = (row < nrows) ? X[(size_t)base * IN + i] : 0.0f;
    }
    __syncthreads();
    int g = tid / TPR;
    int c0 = (tid % TPR) * 4;
    float4 acc[NR];
#pragma unroll
    for (int r = 0; r < NR; ++r) acc[r] = make_float4(0.f, 0.f, 0.f, 0.f);
#pragma unroll 8
    for (int k = 0; k < IN; ++k) {
        float4 w = *(const float4*)&Wl[k * OUT + c0];
#pragma unroll
        for (int r = 0; r < NR; ++r) {
            float a = xl[(g * NR + r) * XS + k];
            acc[r].x += a * w.x; acc[r].y += a * w.y;
            acc[r].z += a * w.z; acc[r].w += a * w.w;
        }
    }
#pragma unroll
    for (int r = 0; r < NR; ++r) {
        int row = base + g * NR + r;
        if (row >= nrows) continue;
        float4 o = acc[r];
        if (EPI == 0) {
            o.x = fmaxf(o.x + bl[c0], 0.f);
            o.y = fmaxf(o.y + bl[c0 + 1], 0.f);
            o.z = fmaxf(o.z + bl[c0 + 2], 0.f);
            o.w = fmaxf(o.w + bl[c0 + 3], 0.f);
        } else {
            float d0 = dinv[row];
            o.x *= d0; o.y *= d0; o.z *= d0; o.w *= d0;
        }
        *(float4*)&Y[(size_t)row * OUT + c0] = o;
    }
}

extern "C" void kernel_launch(void* const* d_in, const int* in_sizes, int n_in,
                              void* d_out, int out_size, void* d_ws, size_t ws_size,
                              hipStream_t stream) {
    const float* x  = (const float*)d_in[0];
    const int*   ei = (const int*)d_in[1];
    const float* W1 = (const float*)d_in[2];  const float* b1 = (const float*)d_in[3];
    const float* W2 = (const float*)d_in[4];  const float* b2 = (const float*)d_in[5];
    const float* W3 = (const float*)d_in[6];  const float* b3 = (const float*)d_in[7];
    const float* W4 = (const float*)d_in[8];  const float* b4 = (const float*)d_in[9];
    const float* W5 = (const float*)d_in[10]; const float* b5 = (const float*)d_in[11];

    const int N = in_sizes[0] / 64;   // 100000
    const int E = in_sizes[1] / 2;    // 1600000
    const int* src = ei;
    const int* dst = ei + E;
    const int nbin = (N + BINW - 1) / BINW;   // 196

    char* ws = (char*)d_ws;
    size_t off = 0;
    auto alloc = [&](size_t bytes) -> void* {
        void* p = ws + off;
        off = (off + bytes + 255) & ~(size_t)255;
        return p;
    };
    float* dinv    = (float*)alloc((size_t)N * 4);
    int*   offs    = (int*)alloc((size_t)(N + 1) * 4);
    int*   binBase = (int*)alloc((size_t)(NBIN_MAX + 1) * 4);
    int*   binCur  = (int*)alloc((size_t)NBIN_MAX * 4);
    int*   csr     = (int*)alloc((size_t)E * 4);
    float* s5      = (float*)alloc((size_t)N * 4);
    float* A       = (float*)alloc((size_t)N * 128 * 4);  // h1 -> h3
    float* B       = (float*)alloc((size_t)N * 64 * 4);   // agg1/s2/s3/s4
    float* C       = (float*)alloc((size_t)N * 64 * 4);   // tmp -> h2
    unsigned* tmp  = (unsigned*)C;

    k_init<<<1, 256, 0, stream>>>(binCur, nbin);
    k_binfill<<<(E + CHUNK - 1) / CHUNK, 256, 0, stream>>>(src, dst, E, nbin, binCur, tmp);
    k_base<<<1, 256, 0, stream>>>(binCur, nbin, binBase);
    k_csr<<<nbin, 256, 0, stream>>>(tmp, binBase, N, nbin, dinv, offs, csr);

    // Layer 1 (agg DEPTH=3, R11 exact)
    k_aggp<64, 3, false, false, true><<<(N + 15) / 16, 256, 0, stream>>>(x, dinv, offs, csr, nullptr, B, N);
    k_gemm<64, 128, 0, 4><<<(N + 31) / 32, 256, 0, stream>>>(B, W1, b1, nullptr, A, N);
    // Layer 2 (agg DEPTH=4)
    k_gemm<128, 64, 1, 2><<<(N + 31) / 32, 256, 0, stream>>>(A, W2, nullptr, dinv, B, N);
    k_aggp<64, 4, true, true, false><<<(N + 15) / 16, 256, 0, stream>>>(B, dinv, offs, csr, b2, C, N);
    // Layer 3
    k_gemm<64, 32, 1, 2><<<(N + 63) / 64, 256, 0, stream>>>(C, W3, nullptr, dinv, B, N);
    k_aggp<32, 4, true, true, false><<<(N + 31) / 32, 256, 0, stream>>>(B, dinv, offs, csr, b3, A, N);
    // Layer 4
    k_gemm<32, 16, 1, 2><<<(N + 127) / 128, 256, 0, stream>>>(A, W4, nullptr, dinv, B, N);
    k_agg16g5<4><<<(N + 63) / 64, 256, 0, stream>>>(B, dinv, offs, csr, b4, W5, s5, N);
    // Layer 5
    k_agg1<<<(N + 255) / 256, 256, 0, stream>>>(s5, dinv, offs, csr, b5, (float*)d_out, N);
}